// Round 3
// baseline (1276.811 us; speedup 1.0000x reference)
//
#include <hip/hip_runtime.h>

#define BLOCK 512
#define TT 8
#define INP 6
#define HDIM 64

typedef _Float16 f16;
typedef __attribute__((ext_vector_type(8))) _Float16 f16x8;
typedef __attribute__((ext_vector_type(16))) float f32x16;
typedef __attribute__((ext_vector_type(4))) int int4v;

// LDS fragment regions, in f16 units. Frag = 512 f16 (1KB): lane l holds 8 f16.
// A-frag for (nt,kt): A[n][k], n = nt*32+(l&31), k = kt*16+(l>>5)*8+e
#define WHH0_F  0
#define WIH1_F  16384
#define WHH1_F  32768
#define WIH0_F  49152
#define WIH1B_F 53248
#define LDS_F16 57344
#define LDS_BYTES (LDS_F16*2 + 66*4)   // + Wfc[64], bfc

__device__ __forceinline__ float sigm(float x){
    return __builtin_amdgcn_rcpf(1.0f + __builtin_exp2f(-1.442695040888963f*x));
}
__device__ __forceinline__ float ftanh(float x){
    return 1.0f - 2.0f*__builtin_amdgcn_rcpf(1.0f + __builtin_exp2f(2.885390081777927f*x));
}
__device__ __forceinline__ unsigned pk2(float a, float b){
    union { f16 h[2]; unsigned u; } uu;
    uu.h[0] = (f16)a; uu.h[1] = (f16)b;   // RNE converts
    return uu.u;
}

__global__ void __launch_bounds__(BLOCK, 2)
lstm_swap(const float* __restrict__ x,
          const float* __restrict__ Wih0, const float* __restrict__ Whh0,
          const float* __restrict__ bih0, const float* __restrict__ bhh0,
          const float* __restrict__ Wih1, const float* __restrict__ Whh1,
          const float* __restrict__ bih1, const float* __restrict__ bhh1,
          const float* __restrict__ Wfc,  const float* __restrict__ bfc,
          float* __restrict__ out)
{
    extern __shared__ char smem[];
    f16*   fh = (f16*)smem;
    float* fw = (float*)(smem + LDS_F16*2);

    const int tid = threadIdx.x;

    // ---- pack weights into A-fragment layout ----
    for (int i = tid; i < 3*16384; i += BLOCK){
        int m = i >> 14, j = i & 16383, fg = j >> 9, jj = j & 511;
        int e = jj & 7, l2 = jj >> 3;
        int nt = fg >> 2, kt = fg & 3;
        int n = nt*32 + (l2 & 31), k = kt*16 + (l2 >> 5)*8 + e;
        const float* W = (m==0)? Whh0 : (m==1)? Wih1 : Whh1;
        int base = (m==0)? WHH0_F : (m==1)? WIH1_F : WHH1_F;
        fh[base + fg*512 + jj] = (f16)W[n*HDIM + k];
    }
    for (int i = tid; i < 4096; i += BLOCK){           // Wih0 (K=16 pad, k=6 = bias)
        int fg = i >> 9, jj = i & 511, e = jj & 7, l2 = jj >> 3;
        int n = fg*32 + (l2 & 31), k = (l2 >> 5)*8 + e;
        float v = (k < INP) ? Wih0[n*INP + k] : (k == INP ? bih0[n] + bhh0[n] : 0.f);
        fh[WIH0_F + fg*512 + jj] = (f16)v;
    }
    for (int i = tid; i < 4096; i += BLOCK){           // L1 bias k-tile (k=64 slot)
        int fg = i >> 9, jj = i & 511, e = jj & 7, l2 = jj >> 3;
        int n = fg*32 + (l2 & 31);
        float v = ((l2 >> 5) == 0 && e == 0) ? bih1[n] + bhh1[n] : 0.f;
        fh[WIH1B_F + fg*512 + jj] = (f16)v;
    }
    if (tid < 64) fw[tid] = Wfc[tid];
    if (tid == 0) fw[64] = bfc[0];
    __syncthreads();

    const int l     = tid & 63;
    const int w     = tid >> 6;
    const int cb    = l & 31;          // batch col within wave's 32 rows
    const int khalf = l >> 5;
    const int brow  = blockIdx.x*(BLOCK/64)*32 + w*32 + cb;

    const float* xrow = x + (size_t)brow*(TT*INP);

#define AFRAG(BASE, IDX) (*(const f16x8*)(fh + (BASE) + (IDX)*512 + l*8))

    int4v h0f[4], h1f[4];
#pragma unroll
    for (int k2=0;k2<4;k2++){ h0f[k2] = (int4v)0; h1f[k2] = (int4v)0; }
    float c0[32], c1[32];
#pragma unroll
    for (int i=0;i<32;i++){ c0[i]=0.f; c1[i]=0.f; }

    // constant B-frag carrying the L1 bias (k=64 -> khalf==0, e==0)
    f16x8 biasb;
#pragma unroll
    for (int i=0;i<8;i++) biasb[i] = (f16)0.f;
    if (khalf == 0) biasb[0] = (f16)1.0f;

    float fc = 0.f;

    // gates + in-register f16 repack (lane<->lane+32 exchange)
#define GATES(CARR, HF, DO_FC)                                                     \
    _Pragma("unroll")                                                              \
    for (int bb=0; bb<4; bb++){                                                    \
        const int nt2 = bb>>1, rbase = 8*(bb&1);                                   \
        float hvv[8];                                                              \
        _Pragma("unroll")                                                          \
        for (int rr=0; rr<8; rr++){                                                \
            const int r = rbase + rr;                                              \
            float iv = sigm (acc[nt2+0][r]);                                       \
            float fv = sigm (acc[nt2+2][r]);                                       \
            float gv = ftanh(acc[nt2+4][r]);                                       \
            float ov = sigm (acc[nt2+6][r]);                                       \
            float cc = fv*CARR[nt2*16+r] + iv*gv;                                  \
            CARR[nt2*16+r] = cc;                                                   \
            float hv = ov*ftanh(cc);                                               \
            hvv[rr] = hv;                                                          \
            if (DO_FC) fc += fw[nt2*32 + (r&3) + 8*(r>>2) + 4*khalf]*hv;           \
        }                                                                          \
        unsigned X0 = pk2(hvv[0],hvv[1]), X1 = pk2(hvv[2],hvv[3]);                 \
        unsigned Y0 = pk2(hvv[4],hvv[5]), Y1 = pk2(hvv[6],hvv[7]);                 \
        unsigned s0 = khalf ? X0 : Y0;                                             \
        unsigned s1 = khalf ? X1 : Y1;                                             \
        unsigned r0 = __shfl_xor(s0, 32);                                          \
        unsigned r1 = __shfl_xor(s1, 32);                                          \
        int F0 = khalf ? (int)r0 : (int)X0;                                        \
        int F1 = khalf ? (int)r1 : (int)X1;                                        \
        int F2 = khalf ? (int)Y0 : (int)r0;                                        \
        int F3 = khalf ? (int)Y1 : (int)r1;                                        \
        HF[bb] = (int4v){F0, F1, F2, F3};                                          \
    }

#pragma unroll 1
    for (int t=0; t<TT; t++){
        // issue x loads early; consumed after the hh0 matmul block
        float2 xv0 = *(const float2*)(xrow + t*INP);
        float2 xv1 = *(const float2*)(xrow + t*INP + 2);
        float2 xv2 = *(const float2*)(xrow + t*INP + 4);

        f32x16 acc[8];
#pragma unroll
        for (int nt=0; nt<8; nt++)
#pragma unroll
            for (int r=0; r<16; r++) acc[nt][r] = 0.f;

        // ---- layer 0: recurrent first (covers x-load latency) ----
#pragma unroll
        for (int kt=0; kt<4; kt++){
            f16x8 b = __builtin_bit_cast(f16x8, h0f[kt]);
#pragma unroll
            for (int nt=0; nt<8; nt++)
                acc[nt] = __builtin_amdgcn_mfma_f32_32x32x16_f16(AFRAG(WHH0_F, nt*4+kt), b, acc[nt], 0,0,0);
        }
        // x (+bias at k=6)
        f16x8 xf;
#pragma unroll
        for (int i=0;i<8;i++) xf[i] = (f16)0.f;
        if (khalf == 0){
            xf[0]=(f16)xv0.x; xf[1]=(f16)xv0.y; xf[2]=(f16)xv1.x;
            xf[3]=(f16)xv1.y; xf[4]=(f16)xv2.x; xf[5]=(f16)xv2.y;
            xf[6]=(f16)1.0f;
        }
#pragma unroll
        for (int nt=0; nt<8; nt++)
            acc[nt] = __builtin_amdgcn_mfma_f32_32x32x16_f16(AFRAG(WIH0_F, nt), xf, acc[nt], 0,0,0);

        GATES(c0, h0f, false)

        // ---- layer 1 ----
#pragma unroll
        for (int nt=0; nt<8; nt++)
#pragma unroll
            for (int r=0; r<16; r++) acc[nt][r] = 0.f;
#pragma unroll
        for (int kt=0; kt<4; kt++){
            f16x8 b = __builtin_bit_cast(f16x8, h0f[kt]);
#pragma unroll
            for (int nt=0; nt<8; nt++)
                acc[nt] = __builtin_amdgcn_mfma_f32_32x32x16_f16(AFRAG(WIH1_F, nt*4+kt), b, acc[nt], 0,0,0);
        }
#pragma unroll
        for (int nt=0; nt<8; nt++)    // bias k-tile
            acc[nt] = __builtin_amdgcn_mfma_f32_32x32x16_f16(AFRAG(WIH1B_F, nt), biasb, acc[nt], 0,0,0);
#pragma unroll
        for (int kt=0; kt<4; kt++){
            f16x8 b = __builtin_bit_cast(f16x8, h1f[kt]);
#pragma unroll
            for (int nt=0; nt<8; nt++)
                acc[nt] = __builtin_amdgcn_mfma_f32_32x32x16_f16(AFRAG(WHH1_F, nt*4+kt), b, acc[nt], 0,0,0);
        }

        GATES(c1, h1f, (t == TT-1))
    }

    // ---- FC epilogue: combine lane<->lane+32 partials ----
    float so = __shfl_xor(fc, 32);
    float tot = fc + so + fw[64];
    if (l < 32)
        out[(size_t)blockIdx.x*(BLOCK/64)*32 + w*32 + l] = tot;
}

extern "C" void kernel_launch(void* const* d_in, const int* in_sizes, int n_in,
                              void* d_out, int out_size, void* d_ws, size_t ws_size,
                              hipStream_t stream) {
    const float* x    = (const float*)d_in[0];
    const float* Wih0 = (const float*)d_in[1];
    const float* Whh0 = (const float*)d_in[2];
    const float* bih0 = (const float*)d_in[3];
    const float* bhh0 = (const float*)d_in[4];
    const float* Wih1 = (const float*)d_in[5];
    const float* Whh1 = (const float*)d_in[6];
    const float* bih1 = (const float*)d_in[7];
    const float* bhh1 = (const float*)d_in[8];
    const float* Wfc  = (const float*)d_in[9];
    const float* bfc  = (const float*)d_in[10];
    float* out = (float*)d_out;

    const int B = in_sizes[0] / (TT*INP);            // 131072
    const int rows_per_block = (BLOCK/64)*32;        // 256
    const size_t shmem = LDS_BYTES;                  // ~114.9 KB
    hipFuncSetAttribute(reinterpret_cast<const void*>(lstm_swap),
                        hipFuncAttributeMaxDynamicSharedMemorySize, (int)shmem);
    lstm_swap<<<dim3(B/rows_per_block), dim3(BLOCK), shmem, stream>>>(
        x, Wih0, Whh0, bih0, bhh0, Wih1, Whh1, bih1, bhh1, Wfc, bfc, out);
}

// Round 4
// 756.108 us; speedup vs baseline: 1.6887x; 1.6887x over previous
//
#include <hip/hip_runtime.h>

#define BLOCK 512
#define TT 8
#define INP 6
#define HDIM 64

typedef _Float16 f16;
typedef __attribute__((ext_vector_type(8))) _Float16 f16x8;
typedef __attribute__((ext_vector_type(16))) float f32x16;
typedef __attribute__((ext_vector_type(4))) int int4v;

// LDS fragment regions, in f16 units. Frag = 512 f16 (1KB): lane l holds 8 f16.
// A-frag for (nt,kt): A[n][k], n = nt*32+(l&31), k = kt*16+(l>>5)*8+e
#define WHH0_F  0
#define WIH1_F  16384
#define WHH1_F  32768
#define WIH0_F  49152
#define WIH1B_F 53248
#define LDS_F16 57344
#define LDS_BYTES (LDS_F16*2 + 66*4)   // + Wfc[64], bfc

__device__ __forceinline__ float sigm(float x){
    return __builtin_amdgcn_rcpf(1.0f + __builtin_exp2f(-1.442695040888963f*x));
}
__device__ __forceinline__ float ftanh(float x){
    return 1.0f - 2.0f*__builtin_amdgcn_rcpf(1.0f + __builtin_exp2f(2.885390081777927f*x));
}
__device__ __forceinline__ unsigned pk2(float a, float b){
    union { f16 h[2]; unsigned u; } uu;
    uu.h[0] = (f16)a; uu.h[1] = (f16)b;   // RNE converts
    return uu.u;
}

__global__ void __launch_bounds__(BLOCK, 1)
lstm_swap(const float* __restrict__ x,
          const float* __restrict__ Wih0, const float* __restrict__ Whh0,
          const float* __restrict__ bih0, const float* __restrict__ bhh0,
          const float* __restrict__ Wih1, const float* __restrict__ Whh1,
          const float* __restrict__ bih1, const float* __restrict__ bhh1,
          const float* __restrict__ Wfc,  const float* __restrict__ bfc,
          float* __restrict__ out)
{
    extern __shared__ char smem[];
    f16*   fh = (f16*)smem;
    float* fw = (float*)(smem + LDS_F16*2);

    const int tid = threadIdx.x;

    // ---- pack weights into A-fragment layout ----
    for (int i = tid; i < 3*16384; i += BLOCK){
        int m = i >> 14, j = i & 16383, fg = j >> 9, jj = j & 511;
        int e = jj & 7, l2 = jj >> 3;
        int nt = fg >> 2, kt = fg & 3;
        int n = nt*32 + (l2 & 31), k = kt*16 + (l2 >> 5)*8 + e;
        const float* W = (m==0)? Whh0 : (m==1)? Wih1 : Whh1;
        int base = (m==0)? WHH0_F : (m==1)? WIH1_F : WHH1_F;
        fh[base + fg*512 + jj] = (f16)W[n*HDIM + k];
    }
    for (int i = tid; i < 4096; i += BLOCK){           // Wih0 (K=16 pad, k=6 = bias)
        int fg = i >> 9, jj = i & 511, e = jj & 7, l2 = jj >> 3;
        int n = fg*32 + (l2 & 31), k = (l2 >> 5)*8 + e;
        float v = (k < INP) ? Wih0[n*INP + k] : (k == INP ? bih0[n] + bhh0[n] : 0.f);
        fh[WIH0_F + fg*512 + jj] = (f16)v;
    }
    for (int i = tid; i < 4096; i += BLOCK){           // L1 bias k-tile (k=64 slot)
        int fg = i >> 9, jj = i & 511, e = jj & 7, l2 = jj >> 3;
        int n = fg*32 + (l2 & 31);
        float v = ((l2 >> 5) == 0 && e == 0) ? bih1[n] + bhh1[n] : 0.f;
        fh[WIH1B_F + fg*512 + jj] = (f16)v;
    }
    if (tid < 64) fw[tid] = Wfc[tid];
    if (tid == 0) fw[64] = bfc[0];
    __syncthreads();

    const int l     = tid & 63;
    const int w     = tid >> 6;
    const int cb    = l & 31;
    const int khalf = l >> 5;
    const int brow  = blockIdx.x*(BLOCK/64)*32 + w*32 + cb;

    const float* xrow = x + (size_t)brow*(TT*INP);

#define AFRAG(BASE, IDX) (*(const f16x8*)(fh + (BASE) + (IDX)*512 + l*8))

// 4-gate MFMA quad against a 32-frag matrix (frag idx nt*4+kt, nt=2g+S)
#define MM4(BASE, S, KT, BOP)                                                        \
    a0 = __builtin_amdgcn_mfma_f32_32x32x16_f16(AFRAG(BASE, ((S)+0)*4+(KT)), BOP, a0, 0,0,0); \
    a1 = __builtin_amdgcn_mfma_f32_32x32x16_f16(AFRAG(BASE, ((S)+2)*4+(KT)), BOP, a1, 0,0,0); \
    a2 = __builtin_amdgcn_mfma_f32_32x32x16_f16(AFRAG(BASE, ((S)+4)*4+(KT)), BOP, a2, 0,0,0); \
    a3 = __builtin_amdgcn_mfma_f32_32x32x16_f16(AFRAG(BASE, ((S)+6)*4+(KT)), BOP, a3, 0,0,0);

// same against an 8-frag (single-kt) matrix: frag idx = 2g+S
#define MM4X(BASE, S, BOP)                                                           \
    a0 = __builtin_amdgcn_mfma_f32_32x32x16_f16(AFRAG(BASE, (S)+0), BOP, a0, 0,0,0); \
    a1 = __builtin_amdgcn_mfma_f32_32x32x16_f16(AFRAG(BASE, (S)+2), BOP, a1, 0,0,0); \
    a2 = __builtin_amdgcn_mfma_f32_32x32x16_f16(AFRAG(BASE, (S)+4), BOP, a2, 0,0,0); \
    a3 = __builtin_amdgcn_mfma_f32_32x32x16_f16(AFRAG(BASE, (S)+6), BOP, a3, 0,0,0);

#define ZERO4()                                                                      \
    _Pragma("unroll") for (int z=0; z<16; z++){ a0[z]=0.f; a1[z]=0.f; a2[z]=0.f; a3[z]=0.f; }

// gates + in-register f16 repack for cell-half S -> HN[2S], HN[2S+1]
#define GHALF(S, CARR, HN, DOFC)                                                     \
    _Pragma("unroll")                                                                \
    for (int rb=0; rb<2; rb++){                                                      \
        float hvv[8];                                                                \
        _Pragma("unroll")                                                            \
        for (int rr=0; rr<8; rr++){                                                  \
            const int r = rb*8+rr;                                                   \
            float iv = sigm (a0[r]);                                                 \
            float fv = sigm (a1[r]);                                                 \
            float gv = ftanh(a2[r]);                                                 \
            float ov = sigm (a3[r]);                                                 \
            float cc = fv*CARR[(S)*16+r] + iv*gv;                                    \
            CARR[(S)*16+r] = cc;                                                     \
            float hv = ov*ftanh(cc);                                                 \
            hvv[rr] = hv;                                                            \
            if (DOFC) fc += fw[(S)*32 + (r&3) + 8*(r>>2) + 4*khalf]*hv;              \
        }                                                                            \
        unsigned X0 = pk2(hvv[0],hvv[1]), X1 = pk2(hvv[2],hvv[3]);                   \
        unsigned Y0 = pk2(hvv[4],hvv[5]), Y1 = pk2(hvv[6],hvv[7]);                   \
        unsigned sa = khalf ? X0 : Y0;                                               \
        unsigned sb = khalf ? X1 : Y1;                                               \
        unsigned ra = __shfl_xor(sa, 32);                                            \
        unsigned rc = __shfl_xor(sb, 32);                                            \
        int F0 = khalf ? (int)ra : (int)X0;                                          \
        int F1 = khalf ? (int)rc : (int)X1;                                          \
        int F2 = khalf ? (int)Y0 : (int)ra;                                          \
        int F3 = khalf ? (int)Y1 : (int)rc;                                          \
        HN[2*(S)+rb] = (int4v){F0, F1, F2, F3};                                      \
    }

    int4v h0f[4], h1f[4], h0n[4], h1n[4];
#pragma unroll
    for (int k2=0;k2<4;k2++){ h0f[k2]=(int4v)0; h1f[k2]=(int4v)0; }
    float c0[32], c1[32];
#pragma unroll
    for (int i=0;i<32;i++){ c0[i]=0.f; c1[i]=0.f; }

    // constant B-frag carrying the L1 bias (k=64 -> khalf==0, e==0)
    f16x8 biasb;
#pragma unroll
    for (int i=0;i<8;i++) biasb[i] = (f16)0.f;
    if (khalf == 0) biasb[0] = (f16)1.0f;

    float fc = 0.f;

#pragma unroll 1
    for (int t=0; t<TT; t++){
        float2 xv0 = *(const float2*)(xrow + t*INP);
        float2 xv1 = *(const float2*)(xrow + t*INP + 2);
        float2 xv2 = *(const float2*)(xrow + t*INP + 4);

        f16x8 xf;
#pragma unroll
        for (int i=0;i<8;i++) xf[i] = (f16)0.f;
        if (khalf == 0){
            xf[0]=(f16)xv0.x; xf[1]=(f16)xv0.y; xf[2]=(f16)xv1.x;
            xf[3]=(f16)xv1.y; xf[4]=(f16)xv2.x; xf[5]=(f16)xv2.y;
            xf[6]=(f16)1.0f;
        }

        f32x16 a0, a1, a2, a3;

        // ================= layer 0 =================
        // pass s=0 (cells 0..31)
        ZERO4()
#pragma unroll
        for (int kt=0; kt<4; kt++){
            f16x8 b = __builtin_bit_cast(f16x8, h0f[kt]);
            MM4(WHH0_F, 0, kt, b)
        }
        MM4X(WIH0_F, 0, xf)
        GHALF(0, c0, h0n, false)
        // pass s=1 (cells 32..63)
        ZERO4()
#pragma unroll
        for (int kt=0; kt<4; kt++){
            f16x8 b = __builtin_bit_cast(f16x8, h0f[kt]);
            MM4(WHH0_F, 1, kt, b)
        }
        MM4X(WIH0_F, 1, xf)
        GHALF(1, c0, h0n, false)
#pragma unroll
        for (int k2=0;k2<4;k2++) h0f[k2] = h0n[k2];

        // ================= layer 1 =================
        const bool last = (t == TT-1);
        // pass s=0
        ZERO4()
#pragma unroll
        for (int kt=0; kt<4; kt++){
            f16x8 b = __builtin_bit_cast(f16x8, h0f[kt]);
            MM4(WIH1_F, 0, kt, b)
        }
        MM4X(WIH1B_F, 0, biasb)
#pragma unroll
        for (int kt=0; kt<4; kt++){
            f16x8 b = __builtin_bit_cast(f16x8, h1f[kt]);
            MM4(WHH1_F, 0, kt, b)
        }
        GHALF(0, c1, h1n, last)
        // pass s=1
        ZERO4()
#pragma unroll
        for (int kt=0; kt<4; kt++){
            f16x8 b = __builtin_bit_cast(f16x8, h0f[kt]);
            MM4(WIH1_F, 1, kt, b)
        }
        MM4X(WIH1B_F, 1, biasb)
#pragma unroll
        for (int kt=0; kt<4; kt++){
            f16x8 b = __builtin_bit_cast(f16x8, h1f[kt]);
            MM4(WHH1_F, 1, kt, b)
        }
        GHALF(1, c1, h1n, last)
#pragma unroll
        for (int k2=0;k2<4;k2++) h1f[k2] = h1n[k2];
    }

    // ---- FC epilogue: combine lane<->lane+32 partials ----
    float so = __shfl_xor(fc, 32);
    float tot = fc + so + fw[64];
    if (l < 32)
        out[(size_t)blockIdx.x*(BLOCK/64)*32 + w*32 + l] = tot;
}

extern "C" void kernel_launch(void* const* d_in, const int* in_sizes, int n_in,
                              void* d_out, int out_size, void* d_ws, size_t ws_size,
                              hipStream_t stream) {
    const float* x    = (const float*)d_in[0];
    const float* Wih0 = (const float*)d_in[1];
    const float* Whh0 = (const float*)d_in[2];
    const float* bih0 = (const float*)d_in[3];
    const float* bhh0 = (const float*)d_in[4];
    const float* Wih1 = (const float*)d_in[5];
    const float* Whh1 = (const float*)d_in[6];
    const float* bih1 = (const float*)d_in[7];
    const float* bhh1 = (const float*)d_in[8];
    const float* Wfc  = (const float*)d_in[9];
    const float* bfc  = (const float*)d_in[10];
    float* out = (float*)d_out;

    const int B = in_sizes[0] / (TT*INP);            // 131072
    const int rows_per_block = (BLOCK/64)*32;        // 256
    const size_t shmem = LDS_BYTES;                  // ~112.3 KB
    hipFuncSetAttribute(reinterpret_cast<const void*>(lstm_swap),
                        hipFuncAttributeMaxDynamicSharedMemorySize, (int)shmem);
    lstm_swap<<<dim3(B/rows_per_block), dim3(BLOCK), shmem, stream>>>(
        x, Wih0, Whh0, bih0, bhh0, Wih1, Whh1, bih1, bhh1, Wfc, bfc, out);
}

// Round 5
// 754.334 us; speedup vs baseline: 1.6926x; 1.0024x over previous
//
#include <hip/hip_runtime.h>

#define BLOCK 512
#define TT 8
#define INP 6
#define HDIM 64

typedef _Float16 f16;
typedef __attribute__((ext_vector_type(8))) _Float16 f16x8;
typedef __attribute__((ext_vector_type(16))) float f32x16;
typedef __attribute__((ext_vector_type(4))) int int4v;

// LDS fragment regions, in f16 units. Frag = 512 f16 (1KB): lane l holds 8 f16.
// A-frag for (nt,kt): A[n][k], n = nt*32+(l&31), k = kt*16+(l>>5)*8+e
#define WHH0_F  0
#define WIH1_F  16384
#define WHH1_F  32768
#define WIH0_F  49152
#define WIH1B_F 53248
#define LDS_F16 57344
#define LDS_BYTES (LDS_F16*2 + 66*4)   // + Wfc[64], bfc

__device__ __forceinline__ float sigm(float x){
    return __builtin_amdgcn_rcpf(1.0f + __builtin_exp2f(-1.442695040888963f*x));
}
__device__ __forceinline__ float ftanh(float x){
    return 1.0f - 2.0f*__builtin_amdgcn_rcpf(1.0f + __builtin_exp2f(2.885390081777927f*x));
}
__device__ __forceinline__ unsigned pk2(float a, float b){
    union { f16 h[2]; unsigned u; } uu;
    uu.h[0] = (f16)a; uu.h[1] = (f16)b;   // RNE converts
    return uu.u;
}

__global__ void
__attribute__((amdgpu_flat_work_group_size(BLOCK, BLOCK), amdgpu_waves_per_eu(2, 2)))
lstm_swap(const float* __restrict__ x,
          const float* __restrict__ Wih0, const float* __restrict__ Whh0,
          const float* __restrict__ bih0, const float* __restrict__ bhh0,
          const float* __restrict__ Wih1, const float* __restrict__ Whh1,
          const float* __restrict__ bih1, const float* __restrict__ bhh1,
          const float* __restrict__ Wfc,  const float* __restrict__ bfc,
          float* __restrict__ out)
{
    extern __shared__ char smem[];
    f16*   fh = (f16*)smem;
    float* fw = (float*)(smem + LDS_F16*2);

    const int tid = threadIdx.x;

    // ---- pack weights into A-fragment layout ----
    for (int i = tid; i < 3*16384; i += BLOCK){
        int m = i >> 14, j = i & 16383, fg = j >> 9, jj = j & 511;
        int e = jj & 7, l2 = jj >> 3;
        int nt = fg >> 2, kt = fg & 3;
        int n = nt*32 + (l2 & 31), k = kt*16 + (l2 >> 5)*8 + e;
        const float* W = (m==0)? Whh0 : (m==1)? Wih1 : Whh1;
        int base = (m==0)? WHH0_F : (m==1)? WIH1_F : WHH1_F;
        fh[base + fg*512 + jj] = (f16)W[n*HDIM + k];
    }
    for (int i = tid; i < 4096; i += BLOCK){           // Wih0 (K=16 pad, k=6 = bias)
        int fg = i >> 9, jj = i & 511, e = jj & 7, l2 = jj >> 3;
        int n = fg*32 + (l2 & 31), k = (l2 >> 5)*8 + e;
        float v = (k < INP) ? Wih0[n*INP + k] : (k == INP ? bih0[n] + bhh0[n] : 0.f);
        fh[WIH0_F + fg*512 + jj] = (f16)v;
    }
    for (int i = tid; i < 4096; i += BLOCK){           // L1 bias k-tile (k=64 slot)
        int fg = i >> 9, jj = i & 511, e = jj & 7, l2 = jj >> 3;
        int n = fg*32 + (l2 & 31);
        float v = ((l2 >> 5) == 0 && e == 0) ? bih1[n] + bhh1[n] : 0.f;
        fh[WIH1B_F + fg*512 + jj] = (f16)v;
    }
    if (tid < 64) fw[tid] = Wfc[tid];
    if (tid == 0) fw[64] = bfc[0];
    __syncthreads();

    const int l     = tid & 63;
    const int w     = tid >> 6;
    const int cb    = l & 31;
    const int khalf = l >> 5;
    const int brow  = blockIdx.x*(BLOCK/64)*32 + w*32 + cb;

    const float* xrow = x + (size_t)brow*(TT*INP);

#define AFRAG(BASE, IDX) (*(const f16x8*)(fh + (BASE) + (IDX)*512 + l*8))

// 4-gate MFMA quad against a 32-frag matrix (frag idx nt*4+kt, nt=2g+S)
#define MM4(BASE, S, KT, BOP)                                                        \
    a0 = __builtin_amdgcn_mfma_f32_32x32x16_f16(AFRAG(BASE, ((S)+0)*4+(KT)), BOP, a0, 0,0,0); \
    a1 = __builtin_amdgcn_mfma_f32_32x32x16_f16(AFRAG(BASE, ((S)+2)*4+(KT)), BOP, a1, 0,0,0); \
    a2 = __builtin_amdgcn_mfma_f32_32x32x16_f16(AFRAG(BASE, ((S)+4)*4+(KT)), BOP, a2, 0,0,0); \
    a3 = __builtin_amdgcn_mfma_f32_32x32x16_f16(AFRAG(BASE, ((S)+6)*4+(KT)), BOP, a3, 0,0,0);

// same against an 8-frag (single-kt) matrix: frag idx = 2g+S
#define MM4X(BASE, S, BOP)                                                           \
    a0 = __builtin_amdgcn_mfma_f32_32x32x16_f16(AFRAG(BASE, (S)+0), BOP, a0, 0,0,0); \
    a1 = __builtin_amdgcn_mfma_f32_32x32x16_f16(AFRAG(BASE, (S)+2), BOP, a1, 0,0,0); \
    a2 = __builtin_amdgcn_mfma_f32_32x32x16_f16(AFRAG(BASE, (S)+4), BOP, a2, 0,0,0); \
    a3 = __builtin_amdgcn_mfma_f32_32x32x16_f16(AFRAG(BASE, (S)+6), BOP, a3, 0,0,0);

#define ZERO4()                                                                      \
    _Pragma("unroll") for (int z=0; z<16; z++){ a0[z]=0.f; a1[z]=0.f; a2[z]=0.f; a3[z]=0.f; }

// gates + in-register f16 repack for cell-half S -> HN[2S], HN[2S+1]
#define GHALF(S, CARR, HN, DOFC)                                                     \
    _Pragma("unroll")                                                                \
    for (int rb=0; rb<2; rb++){                                                      \
        float hvv[8];                                                                \
        _Pragma("unroll")                                                            \
        for (int rr=0; rr<8; rr++){                                                  \
            const int r = rb*8+rr;                                                   \
            float iv = sigm (a0[r]);                                                 \
            float fv = sigm (a1[r]);                                                 \
            float gv = ftanh(a2[r]);                                                 \
            float ov = sigm (a3[r]);                                                 \
            float cc = fv*CARR[(S)*16+r] + iv*gv;                                    \
            CARR[(S)*16+r] = cc;                                                     \
            float hv = ov*ftanh(cc);                                                 \
            hvv[rr] = hv;                                                            \
            if (DOFC) fc += fw[(S)*32 + (r&3) + 8*(r>>2) + 4*khalf]*hv;              \
        }                                                                            \
        unsigned X0 = pk2(hvv[0],hvv[1]), X1 = pk2(hvv[2],hvv[3]);                   \
        unsigned Y0 = pk2(hvv[4],hvv[5]), Y1 = pk2(hvv[6],hvv[7]);                   \
        unsigned sa = khalf ? X0 : Y0;                                               \
        unsigned sb = khalf ? X1 : Y1;                                               \
        unsigned ra = __shfl_xor(sa, 32);                                            \
        unsigned rc = __shfl_xor(sb, 32);                                            \
        int F0 = khalf ? (int)ra : (int)X0;                                          \
        int F1 = khalf ? (int)rc : (int)X1;                                          \
        int F2 = khalf ? (int)Y0 : (int)ra;                                          \
        int F3 = khalf ? (int)Y1 : (int)rc;                                          \
        HN[2*(S)+rb] = (int4v){F0, F1, F2, F3};                                      \
    }

    int4v h0f[4], h1f[4], h0n[4], h1n[4];
#pragma unroll
    for (int k2=0;k2<4;k2++){ h0f[k2]=(int4v)0; h1f[k2]=(int4v)0; }
    float c0[32], c1[32];
#pragma unroll
    for (int i=0;i<32;i++){ c0[i]=0.f; c1[i]=0.f; }

    // constant B-frag carrying the L1 bias (k=64 -> khalf==0, e==0)
    f16x8 biasb;
#pragma unroll
    for (int i=0;i<8;i++) biasb[i] = (f16)0.f;
    if (khalf == 0) biasb[0] = (f16)1.0f;

    float fc = 0.f;

#pragma unroll 1
    for (int t=0; t<TT; t++){
        float2 xv0 = *(const float2*)(xrow + t*INP);
        float2 xv1 = *(const float2*)(xrow + t*INP + 2);
        float2 xv2 = *(const float2*)(xrow + t*INP + 4);

        f16x8 xf;
#pragma unroll
        for (int i=0;i<8;i++) xf[i] = (f16)0.f;
        if (khalf == 0){
            xf[0]=(f16)xv0.x; xf[1]=(f16)xv0.y; xf[2]=(f16)xv1.x;
            xf[3]=(f16)xv1.y; xf[4]=(f16)xv2.x; xf[5]=(f16)xv2.y;
            xf[6]=(f16)1.0f;
        }

        f32x16 a0, a1, a2, a3;

        // ================= layer 0 =================
        // pass s=0 (cells 0..31)
        ZERO4()
#pragma unroll
        for (int kt=0; kt<4; kt++){
            f16x8 b = __builtin_bit_cast(f16x8, h0f[kt]);
            MM4(WHH0_F, 0, kt, b)
        }
        MM4X(WIH0_F, 0, xf)
        GHALF(0, c0, h0n, false)
        // pass s=1 (cells 32..63)
        ZERO4()
#pragma unroll
        for (int kt=0; kt<4; kt++){
            f16x8 b = __builtin_bit_cast(f16x8, h0f[kt]);
            MM4(WHH0_F, 1, kt, b)
        }
        MM4X(WIH0_F, 1, xf)
        GHALF(1, c0, h0n, false)
#pragma unroll
        for (int k2=0;k2<4;k2++) h0f[k2] = h0n[k2];

        // ================= layer 1 =================
        const bool last = (t == TT-1);
        // pass s=0
        ZERO4()
#pragma unroll
        for (int kt=0; kt<4; kt++){
            f16x8 b = __builtin_bit_cast(f16x8, h0f[kt]);
            MM4(WIH1_F, 0, kt, b)
        }
        MM4X(WIH1B_F, 0, biasb)
#pragma unroll
        for (int kt=0; kt<4; kt++){
            f16x8 b = __builtin_bit_cast(f16x8, h1f[kt]);
            MM4(WHH1_F, 0, kt, b)
        }
        GHALF(0, c1, h1n, last)
        // pass s=1
        ZERO4()
#pragma unroll
        for (int kt=0; kt<4; kt++){
            f16x8 b = __builtin_bit_cast(f16x8, h0f[kt]);
            MM4(WIH1_F, 1, kt, b)
        }
        MM4X(WIH1B_F, 1, biasb)
#pragma unroll
        for (int kt=0; kt<4; kt++){
            f16x8 b = __builtin_bit_cast(f16x8, h1f[kt]);
            MM4(WHH1_F, 1, kt, b)
        }
        GHALF(1, c1, h1n, last)
#pragma unroll
        for (int k2=0;k2<4;k2++) h1f[k2] = h1n[k2];
    }

    // ---- FC epilogue: combine lane<->lane+32 partials ----
    float so = __shfl_xor(fc, 32);
    float tot = fc + so + fw[64];
    if (l < 32)
        out[(size_t)blockIdx.x*(BLOCK/64)*32 + w*32 + l] = tot;
}

extern "C" void kernel_launch(void* const* d_in, const int* in_sizes, int n_in,
                              void* d_out, int out_size, void* d_ws, size_t ws_size,
                              hipStream_t stream) {
    const float* x    = (const float*)d_in[0];
    const float* Wih0 = (const float*)d_in[1];
    const float* Whh0 = (const float*)d_in[2];
    const float* bih0 = (const float*)d_in[3];
    const float* bhh0 = (const float*)d_in[4];
    const float* Wih1 = (const float*)d_in[5];
    const float* Whh1 = (const float*)d_in[6];
    const float* bih1 = (const float*)d_in[7];
    const float* bhh1 = (const float*)d_in[8];
    const float* Wfc  = (const float*)d_in[9];
    const float* bfc  = (const float*)d_in[10];
    float* out = (float*)d_out;

    const int B = in_sizes[0] / (TT*INP);            // 131072
    const int rows_per_block = (BLOCK/64)*32;        // 256
    const size_t shmem = LDS_BYTES;                  // ~112.3 KB
    hipFuncSetAttribute(reinterpret_cast<const void*>(lstm_swap),
                        hipFuncAttributeMaxDynamicSharedMemorySize, (int)shmem);
    lstm_swap<<<dim3(B/rows_per_block), dim3(BLOCK), shmem, stream>>>(
        x, Wih0, Whh0, bih0, bhh0, Wih1, Whh1, bih1, bhh1, Wfc, bfc, out);
}

// Round 6
// 448.114 us; speedup vs baseline: 2.8493x; 1.6834x over previous
//
#include <hip/hip_runtime.h>

#define BLOCK 512
#define TT 8
#define INP 6
#define HDIM 64

typedef _Float16 f16;
typedef __attribute__((ext_vector_type(8))) _Float16 f16x8;
typedef __attribute__((ext_vector_type(16))) float f32x16;
typedef __attribute__((ext_vector_type(4))) int int4v;

// LDS fragment regions, in f16 units. Frag = 512 f16 (1KB): lane l holds 8 f16.
// A-frag for (nt,kt): A[n][k], n = nt*32+(l&31), k = kt*16+(l>>5)*8+e
#define WHH0_F  0
#define WIH1_F  16384
#define WHH1_F  32768
#define WIH0_F  49152
#define WIH1B_F 53248
#define LDS_F16 57344
#define LDS_BYTES (LDS_F16*2 + 66*4)   // + Wfc[64], bfc

__device__ __forceinline__ float sigm(float x){
    return __builtin_amdgcn_rcpf(1.0f + __builtin_exp2f(-1.442695040888963f*x));
}
__device__ __forceinline__ float ftanh(float x){
    return 1.0f - 2.0f*__builtin_amdgcn_rcpf(1.0f + __builtin_exp2f(2.885390081777927f*x));
}
__device__ __forceinline__ unsigned pk2(float a, float b){
    union { f16 h[2]; unsigned u; } uu;
    uu.h[0] = (f16)a; uu.h[1] = (f16)b;   // RNE converts
    return uu.u;
}

// ---- AGPR parking: force persistent state into the accumulator half of the
// unified RF so the arch-VGPR side stays under the allocator's 128 cap. ----
__device__ __forceinline__ float ag_wf(float v){ float r; asm("v_accvgpr_write_b32 %0, %1" : "=a"(r) : "v"(v)); return r; }
__device__ __forceinline__ float ag_rf(float a){ float r; asm("v_accvgpr_read_b32 %0, %1" : "=v"(r) : "a"(a)); return r; }
__device__ __forceinline__ int   ag_wi(int v){ int r; asm("v_accvgpr_write_b32 %0, %1" : "=a"(r) : "v"(v)); return r; }
__device__ __forceinline__ int   ag_ri(int a){ int r; asm("v_accvgpr_read_b32 %0, %1" : "=v"(r) : "a"(a)); return r; }

__global__ void
__attribute__((amdgpu_flat_work_group_size(BLOCK, BLOCK), amdgpu_waves_per_eu(2, 2)))
lstm_swap(const float* __restrict__ x,
          const float* __restrict__ Wih0, const float* __restrict__ Whh0,
          const float* __restrict__ bih0, const float* __restrict__ bhh0,
          const float* __restrict__ Wih1, const float* __restrict__ Whh1,
          const float* __restrict__ bih1, const float* __restrict__ bhh1,
          const float* __restrict__ Wfc,  const float* __restrict__ bfc,
          float* __restrict__ out)
{
    extern __shared__ char smem[];
    f16*   fh = (f16*)smem;
    float* fw = (float*)(smem + LDS_F16*2);

    const int tid = threadIdx.x;

    // ---- pack weights into A-fragment layout ----
    for (int i = tid; i < 3*16384; i += BLOCK){
        int m = i >> 14, j = i & 16383, fg = j >> 9, jj = j & 511;
        int e = jj & 7, l2 = jj >> 3;
        int nt = fg >> 2, kt = fg & 3;
        int n = nt*32 + (l2 & 31), k = kt*16 + (l2 >> 5)*8 + e;
        const float* W = (m==0)? Whh0 : (m==1)? Wih1 : Whh1;
        int base = (m==0)? WHH0_F : (m==1)? WIH1_F : WHH1_F;
        fh[base + fg*512 + jj] = (f16)W[n*HDIM + k];
    }
    for (int i = tid; i < 4096; i += BLOCK){           // Wih0 (K=16 pad, k=6 = bias)
        int fg = i >> 9, jj = i & 511, e = jj & 7, l2 = jj >> 3;
        int n = fg*32 + (l2 & 31), k = (l2 >> 5)*8 + e;
        float v = (k < INP) ? Wih0[n*INP + k] : (k == INP ? bih0[n] + bhh0[n] : 0.f);
        fh[WIH0_F + fg*512 + jj] = (f16)v;
    }
    for (int i = tid; i < 4096; i += BLOCK){           // L1 bias k-tile (k=64 slot)
        int fg = i >> 9, jj = i & 511, e = jj & 7, l2 = jj >> 3;
        int n = fg*32 + (l2 & 31);
        float v = ((l2 >> 5) == 0 && e == 0) ? bih1[n] + bhh1[n] : 0.f;
        fh[WIH1B_F + fg*512 + jj] = (f16)v;
    }
    if (tid < 64) fw[tid] = Wfc[tid];
    if (tid == 0) fw[64] = bfc[0];
    __syncthreads();

    const int l     = tid & 63;
    const int w     = tid >> 6;
    const int cb    = l & 31;
    const int khalf = l >> 5;
    const int brow  = blockIdx.x*(BLOCK/64)*32 + w*32 + cb;

    const float* xrow = x + (size_t)brow*(TT*INP);

#define AFRAG(BASE, IDX) (*(const f16x8*)(fh + (BASE) + (IDX)*512 + l*8))

// assemble a B-frag from 4 parked AGPR words
#define LOADB(HF, KT) __builtin_bit_cast(f16x8, (int4v){ag_ri(HF[KT][0]), ag_ri(HF[KT][1]), ag_ri(HF[KT][2]), ag_ri(HF[KT][3])})

// 4-gate MFMA quad against a 32-frag matrix (frag idx nt*4+kt, nt=2g+S)
#define MM4(BASE, S, KT, BOP)                                                        \
    a0 = __builtin_amdgcn_mfma_f32_32x32x16_f16(AFRAG(BASE, ((S)+0)*4+(KT)), BOP, a0, 0,0,0); \
    a1 = __builtin_amdgcn_mfma_f32_32x32x16_f16(AFRAG(BASE, ((S)+2)*4+(KT)), BOP, a1, 0,0,0); \
    a2 = __builtin_amdgcn_mfma_f32_32x32x16_f16(AFRAG(BASE, ((S)+4)*4+(KT)), BOP, a2, 0,0,0); \
    a3 = __builtin_amdgcn_mfma_f32_32x32x16_f16(AFRAG(BASE, ((S)+6)*4+(KT)), BOP, a3, 0,0,0);

// same against an 8-frag (single-kt) matrix: frag idx = 2g+S
#define MM4X(BASE, S, BOP)                                                           \
    a0 = __builtin_amdgcn_mfma_f32_32x32x16_f16(AFRAG(BASE, (S)+0), BOP, a0, 0,0,0); \
    a1 = __builtin_amdgcn_mfma_f32_32x32x16_f16(AFRAG(BASE, (S)+2), BOP, a1, 0,0,0); \
    a2 = __builtin_amdgcn_mfma_f32_32x32x16_f16(AFRAG(BASE, (S)+4), BOP, a2, 0,0,0); \
    a3 = __builtin_amdgcn_mfma_f32_32x32x16_f16(AFRAG(BASE, (S)+6), BOP, a3, 0,0,0);

#define ZERO4()                                                                      \
    _Pragma("unroll") for (int z=0; z<16; z++){ a0[z]=0.f; a1[z]=0.f; a2[z]=0.f; a3[z]=0.f; }

// gates + in-register f16 repack for cell-half S -> HN[2S], HN[2S+1]
// c state lives in AGPRs (ag_rf/ag_wf round-trip)
#define GHALF(S, CARR, HN, DOFC)                                                     \
    _Pragma("unroll")                                                                \
    for (int rb=0; rb<2; rb++){                                                      \
        float hvv[8];                                                                \
        _Pragma("unroll")                                                            \
        for (int rr=0; rr<8; rr++){                                                  \
            const int r = rb*8+rr;                                                   \
            float iv = sigm (a0[r]);                                                 \
            float fv = sigm (a1[r]);                                                 \
            float gv = ftanh(a2[r]);                                                 \
            float ov = sigm (a3[r]);                                                 \
            float cc = fv*ag_rf(CARR[(S)*16+r]) + iv*gv;                             \
            CARR[(S)*16+r] = ag_wf(cc);                                              \
            float hv = ov*ftanh(cc);                                                 \
            hvv[rr] = hv;                                                            \
            if (DOFC) fc += fw[(S)*32 + (r&3) + 8*(r>>2) + 4*khalf]*hv;              \
        }                                                                            \
        unsigned X0 = pk2(hvv[0],hvv[1]), X1 = pk2(hvv[2],hvv[3]);                   \
        unsigned Y0 = pk2(hvv[4],hvv[5]), Y1 = pk2(hvv[6],hvv[7]);                   \
        unsigned sa = khalf ? X0 : Y0;                                               \
        unsigned sb = khalf ? X1 : Y1;                                               \
        unsigned ra = __shfl_xor(sa, 32);                                            \
        unsigned rc = __shfl_xor(sb, 32);                                            \
        int F0 = khalf ? (int)ra : (int)X0;                                          \
        int F1 = khalf ? (int)rc : (int)X1;                                          \
        int F2 = khalf ? (int)Y0 : (int)ra;                                          \
        int F3 = khalf ? (int)Y1 : (int)rc;                                          \
        HN[2*(S)+rb] = (int4v){F0, F1, F2, F3};                                      \
    }

    // persistent state parked in AGPRs
    float c0[32], c1[32];
#pragma unroll
    for (int i=0;i<32;i++){ c0[i]=ag_wf(0.f); c1[i]=ag_wf(0.f); }
    int h0f[4][4], h1f[4][4];
#pragma unroll
    for (int k2=0;k2<4;k2++)
#pragma unroll
        for (int j=0;j<4;j++){ h0f[k2][j]=ag_wi(0); h1f[k2][j]=ag_wi(0); }

    int4v h0n[4], h1n[4];   // transient (arch VGPR)

    // constant B-frag carrying the L1 bias (k=64 -> khalf==0, e==0)
    f16x8 biasb;
#pragma unroll
    for (int i=0;i<8;i++) biasb[i] = (f16)0.f;
    if (khalf == 0) biasb[0] = (f16)1.0f;

    float fc = 0.f;

#pragma unroll 1
    for (int t=0; t<TT; t++){
        float2 xv0 = *(const float2*)(xrow + t*INP);
        float2 xv1 = *(const float2*)(xrow + t*INP + 2);
        float2 xv2 = *(const float2*)(xrow + t*INP + 4);

        f16x8 xf;
#pragma unroll
        for (int i=0;i<8;i++) xf[i] = (f16)0.f;
        if (khalf == 0){
            xf[0]=(f16)xv0.x; xf[1]=(f16)xv0.y; xf[2]=(f16)xv1.x;
            xf[3]=(f16)xv1.y; xf[4]=(f16)xv2.x; xf[5]=(f16)xv2.y;
            xf[6]=(f16)1.0f;
        }

        f32x16 a0, a1, a2, a3;

        // ================= layer 0 =================
        // pass s=0 (cells 0..31)
        ZERO4()
        if (t > 0){
#pragma unroll
            for (int kt=0; kt<4; kt++){
                f16x8 b = LOADB(h0f, kt);
                MM4(WHH0_F, 0, kt, b)
            }
        }
        MM4X(WIH0_F, 0, xf)
        GHALF(0, c0, h0n, false)
        // pass s=1 (cells 32..63)
        ZERO4()
        if (t > 0){
#pragma unroll
            for (int kt=0; kt<4; kt++){
                f16x8 b = LOADB(h0f, kt);
                MM4(WHH0_F, 1, kt, b)
            }
        }
        MM4X(WIH0_F, 1, xf)
        GHALF(1, c0, h0n, false)
#pragma unroll
        for (int k2=0;k2<4;k2++)
#pragma unroll
            for (int j=0;j<4;j++) h0f[k2][j] = ag_wi(h0n[k2][j]);

        // ================= layer 1 =================
        const bool last = (t == TT-1);
        // pass s=0
        ZERO4()
#pragma unroll
        for (int kt=0; kt<4; kt++){
            f16x8 b = LOADB(h0f, kt);
            MM4(WIH1_F, 0, kt, b)
        }
        MM4X(WIH1B_F, 0, biasb)
        if (t > 0){
#pragma unroll
            for (int kt=0; kt<4; kt++){
                f16x8 b = LOADB(h1f, kt);
                MM4(WHH1_F, 0, kt, b)
            }
        }
        GHALF(0, c1, h1n, last)
        // pass s=1
        ZERO4()
#pragma unroll
        for (int kt=0; kt<4; kt++){
            f16x8 b = LOADB(h0f, kt);
            MM4(WIH1_F, 1, kt, b)
        }
        MM4X(WIH1B_F, 1, biasb)
        if (t > 0){
#pragma unroll
            for (int kt=0; kt<4; kt++){
                f16x8 b = LOADB(h1f, kt);
                MM4(WHH1_F, 1, kt, b)
            }
        }
        GHALF(1, c1, h1n, last)
#pragma unroll
        for (int k2=0;k2<4;k2++)
#pragma unroll
            for (int j=0;j<4;j++) h1f[k2][j] = ag_wi(h1n[k2][j]);
    }

    // ---- FC epilogue: combine lane<->lane+32 partials ----
    float so = __shfl_xor(fc, 32);
    float tot = fc + so + fw[64];
    if (l < 32)
        out[(size_t)blockIdx.x*(BLOCK/64)*32 + w*32 + l] = tot;
}

extern "C" void kernel_launch(void* const* d_in, const int* in_sizes, int n_in,
                              void* d_out, int out_size, void* d_ws, size_t ws_size,
                              hipStream_t stream) {
    const float* x    = (const float*)d_in[0];
    const float* Wih0 = (const float*)d_in[1];
    const float* Whh0 = (const float*)d_in[2];
    const float* bih0 = (const float*)d_in[3];
    const float* bhh0 = (const float*)d_in[4];
    const float* Wih1 = (const float*)d_in[5];
    const float* Whh1 = (const float*)d_in[6];
    const float* bih1 = (const float*)d_in[7];
    const float* bhh1 = (const float*)d_in[8];
    const float* Wfc  = (const float*)d_in[9];
    const float* bfc  = (const float*)d_in[10];
    float* out = (float*)d_out;

    const int B = in_sizes[0] / (TT*INP);            // 131072
    const int rows_per_block = (BLOCK/64)*32;        // 256
    const size_t shmem = LDS_BYTES;                  // ~112.3 KB
    hipFuncSetAttribute(reinterpret_cast<const void*>(lstm_swap),
                        hipFuncAttributeMaxDynamicSharedMemorySize, (int)shmem);
    lstm_swap<<<dim3(B/rows_per_block), dim3(BLOCK), shmem, stream>>>(
        x, Wih0, Whh0, bih0, bhh0, Wih1, Whh1, bih1, bhh1, Wfc, bfc, out);
}